// Round 12
// baseline (135.895 us; speedup 1.0000x reference)
//
#include <hip/hip_runtime.h>
#include <hip/hip_bf16.h>

#define LOG2E_F 1.4426950408889634f

typedef __attribute__((ext_vector_type(8))) short short8;
typedef __attribute__((ext_vector_type(4))) float f32x4;

__device__ inline unsigned short f2b(float f) {
    __hip_bfloat16 h = __float2bfloat16(f);   // RNE
    return *reinterpret_cast<unsigned short*>(&h);
}

__device__ inline short8 load_frag_f32(const float* p) {
    const float4 lo = *(const float4*)p;
    const float4 hi = *(const float4*)(p + 4);
    short8 r;
    r[0] = (short)f2b(lo.x); r[1] = (short)f2b(lo.y);
    r[2] = (short)f2b(lo.z); r[3] = (short)f2b(lo.w);
    r[4] = (short)f2b(hi.x); r[5] = (short)f2b(hi.y);
    r[6] = (short)f2b(hi.z); r[7] = (short)f2b(hi.w);
    return r;
}

// =====================================================================
// R11 champion kernel, templated for PHASE ABLATION (diagnostic round).
// NPHASE=1: QKV projection only (+asm sinks).  NPHASE=2: +attention.
// NPHASE=3: full (writes out).  REPS repeats the live region so each
// ablated dispatch exceeds the ~40us harness-fill rows in the profile.
// Kernel math for NPHASE=3 is bit-identical to round 11.
// =====================================================================
template<int NPHASE, int REPS>
__global__ __launch_bounds__(512, 2) void fused2_kernel(
    const float* __restrict__ x, const float* __restrict__ Win,
    const float* __restrict__ bin, const float* __restrict__ Wout,
    const float* __restrict__ bout, const float* __restrict__ alpha,
    const float* __restrict__ dist2, float* __restrict__ out)
{
    __shared__ float qkvl[2][3][32][164];        // 123.0 KB
    __shared__ unsigned short aggb[2][32][136];  //  17.0 KB

    const int tid  = threadIdx.x;                // 0..511
    const int g    = tid >> 8;                   // system group 0/1
    const int t    = tid & 255;
    const int sys  = blockIdx.x * 2 + g;
    const int lane = t & 63;
    const int wv   = t >> 6;                     // wave within group, 0..3
    const int r16  = lane & 15;
    const int kg   = lane >> 4;
    const int base = sys << 5;
    const int qi   = t >> 3;
    const int h    = t & 7;
    const float al2 = alpha[(size_t)(base + qi) * 8 + h] * LOG2E_F;   // < 0

    for (int rep = 0; rep < REPS; ++rep) {

        // ---------------- Phase 1: QKV projection into LDS[g] ----------
        short8 af[2][4];
        #pragma unroll
        for (int rt = 0; rt < 2; ++rt)
            #pragma unroll
            for (int ks = 0; ks < 4; ++ks)
                af[rt][ks] = load_frag_f32(
                    x + (size_t)(base + rt * 16 + r16) * 128 + ks * 32 + kg * 8);

        #pragma unroll
        for (int j = 0; j < 6; ++j) {
            const int ct = wv * 6 + j;            // 0..23 (wave-uniform)
            const int c  = ct * 16 + r16;         // global col 0..383
            short8 bf[4];
            #pragma unroll
            for (int ks = 0; ks < 4; ++ks)
                bf[ks] = load_frag_f32(Win + (size_t)c * 128 + ks * 32 + kg * 8);
            const float bias_v = bin[c];
            const int   bufi   = ct >> 3;         // 0=q, 1=k, 2=v
            const int   hh     = ct & 7;
            const float scale  = (bufi == 0) ? (0.25f * LOG2E_F) : 1.0f;

            #pragma unroll
            for (int rt = 0; rt < 2; ++rt) {
                f32x4 acc = {0.f, 0.f, 0.f, 0.f};
                #pragma unroll
                for (int ks = 0; ks < 4; ++ks)
                    acc = __builtin_amdgcn_mfma_f32_16x16x32_bf16(af[rt][ks], bf[ks], acc, 0, 0, 0);
                #pragma unroll
                for (int r = 0; r < 4; ++r) {
                    const int atom = rt * 16 + kg * 4 + r;
                    qkvl[g][bufi][atom][hh * 20 + r16] = (acc[r] + bias_v) * scale;
                }
            }
        }

        __syncthreads();

        if constexpr (NPHASE == 1) {
            // keep phase-1 work observable without running phase 2 (rule #17)
            const float s0 = qkvl[g][0][qi][h * 20];
            const float s1 = qkvl[g][1][qi][h * 20 + 1];
            const float s2 = qkvl[g][2][qi][h * 20 + 2];
            asm volatile("" :: "v"(s0), "v"(s1), "v"(s2));
        }

        if constexpr (NPHASE >= 2) {
            // ------------- Phase 2: attention (fixed-shift softmax) -----
            float qreg[16];
            {
                const float* qrow = &qkvl[g][0][qi][h * 20];
                #pragma unroll
                for (int d4 = 0; d4 < 4; ++d4) {
                    const float4 tq = *(const float4*)(qrow + (d4 << 2));
                    qreg[d4 * 4 + 0] = tq.x; qreg[d4 * 4 + 1] = tq.y;
                    qreg[d4 * 4 + 2] = tq.z; qreg[d4 * 4 + 3] = tq.w;
                }
            }

            float den = 0.f;
            float acc[16] = {};
            const float* dp = dist2 + (size_t)(sys * 1024 + qi * 32) * 16;

            #pragma unroll 4
            for (int kj = 0; kj < 32; ++kj, dp += 16) {
                const float4 t0 = *(const float4*)(dp + 0);
                const float4 t1 = *(const float4*)(dp + 4);
                const float4 t2 = *(const float4*)(dp + 8);
                const float4 t3 = *(const float4*)(dp + 12);
                const float mn = fminf(
                    fminf(fminf(fminf(t0.x, t0.y), fminf(t0.z, t0.w)),
                          fminf(fminf(t1.x, t1.y), fminf(t1.z, t1.w))),
                    fminf(fminf(fminf(t2.x, t2.y), fminf(t2.z, t2.w)),
                          fminf(fminf(t3.x, t3.y), fminf(t3.z, t3.w))));
                const float c0 = al2 * mn;
                float e0 = __builtin_amdgcn_exp2f(fmaf(al2, t0.x, -c0));
                e0 += __builtin_amdgcn_exp2f(fmaf(al2, t0.y, -c0));
                e0 += __builtin_amdgcn_exp2f(fmaf(al2, t0.z, -c0));
                e0 += __builtin_amdgcn_exp2f(fmaf(al2, t0.w, -c0));
                float e1 = __builtin_amdgcn_exp2f(fmaf(al2, t1.x, -c0));
                e1 += __builtin_amdgcn_exp2f(fmaf(al2, t1.y, -c0));
                e1 += __builtin_amdgcn_exp2f(fmaf(al2, t1.z, -c0));
                e1 += __builtin_amdgcn_exp2f(fmaf(al2, t1.w, -c0));
                float e2 = __builtin_amdgcn_exp2f(fmaf(al2, t2.x, -c0));
                e2 += __builtin_amdgcn_exp2f(fmaf(al2, t2.y, -c0));
                e2 += __builtin_amdgcn_exp2f(fmaf(al2, t2.z, -c0));
                e2 += __builtin_amdgcn_exp2f(fmaf(al2, t2.w, -c0));
                float e3 = __builtin_amdgcn_exp2f(fmaf(al2, t3.x, -c0));
                e3 += __builtin_amdgcn_exp2f(fmaf(al2, t3.y, -c0));
                e3 += __builtin_amdgcn_exp2f(fmaf(al2, t3.z, -c0));
                e3 += __builtin_amdgcn_exp2f(fmaf(al2, t3.w, -c0));
                const float ssum = (e0 + e1) + (e2 + e3);   // in [1, 16]

                const float* kr = &qkvl[g][1][kj][h * 20];
                const float4 k0 = *(const float4*)(kr + 0);
                const float4 k1 = *(const float4*)(kr + 4);
                const float4 k2 = *(const float4*)(kr + 8);
                const float4 k3 = *(const float4*)(kr + 12);
                float p0 = qreg[0] * k0.x, p1 = qreg[1] * k0.y;
                float p2 = qreg[2] * k0.z, p3 = qreg[3] * k0.w;
                p0 = fmaf(qreg[4],  k1.x, p0); p1 = fmaf(qreg[5],  k1.y, p1);
                p2 = fmaf(qreg[6],  k1.z, p2); p3 = fmaf(qreg[7],  k1.w, p3);
                p0 = fmaf(qreg[8],  k2.x, p0); p1 = fmaf(qreg[9],  k2.y, p1);
                p2 = fmaf(qreg[10], k2.z, p2); p3 = fmaf(qreg[11], k2.w, p3);
                p0 = fmaf(qreg[12], k3.x, p0); p1 = fmaf(qreg[13], k3.y, p1);
                p2 = fmaf(qreg[14], k3.z, p2); p3 = fmaf(qreg[15], k3.w, p3);
                const float dot = (p0 + p1) + (p2 + p3);   // log2-domain

                const float b = dot + c0;
                const float p = __builtin_amdgcn_exp2f(b - 16.0f) * ssum;
                den += p;

                const float* vr = &qkvl[g][2][kj][h * 20];
                const float4 v0 = *(const float4*)(vr + 0);
                const float4 v1 = *(const float4*)(vr + 4);
                const float4 v2 = *(const float4*)(vr + 8);
                const float4 v3 = *(const float4*)(vr + 12);
                acc[0]  = fmaf(p, v0.x, acc[0]);  acc[1]  = fmaf(p, v0.y, acc[1]);
                acc[2]  = fmaf(p, v0.z, acc[2]);  acc[3]  = fmaf(p, v0.w, acc[3]);
                acc[4]  = fmaf(p, v1.x, acc[4]);  acc[5]  = fmaf(p, v1.y, acc[5]);
                acc[6]  = fmaf(p, v1.z, acc[6]);  acc[7]  = fmaf(p, v1.w, acc[7]);
                acc[8]  = fmaf(p, v2.x, acc[8]);  acc[9]  = fmaf(p, v2.y, acc[9]);
                acc[10] = fmaf(p, v2.z, acc[10]); acc[11] = fmaf(p, v2.w, acc[11]);
                acc[12] = fmaf(p, v3.x, acc[12]); acc[13] = fmaf(p, v3.y, acc[13]);
                acc[14] = fmaf(p, v3.z, acc[14]); acc[15] = fmaf(p, v3.w, acc[15]);
            }

            {
                const float inv = 1.0f / den;
                unsigned short* op = &aggb[g][qi][h * 16];
                uint4 o0, o1;
                o0.x = (unsigned)f2b(acc[0]  * inv) | ((unsigned)f2b(acc[1]  * inv) << 16);
                o0.y = (unsigned)f2b(acc[2]  * inv) | ((unsigned)f2b(acc[3]  * inv) << 16);
                o0.z = (unsigned)f2b(acc[4]  * inv) | ((unsigned)f2b(acc[5]  * inv) << 16);
                o0.w = (unsigned)f2b(acc[6]  * inv) | ((unsigned)f2b(acc[7]  * inv) << 16);
                o1.x = (unsigned)f2b(acc[8]  * inv) | ((unsigned)f2b(acc[9]  * inv) << 16);
                o1.y = (unsigned)f2b(acc[10] * inv) | ((unsigned)f2b(acc[11] * inv) << 16);
                o1.z = (unsigned)f2b(acc[12] * inv) | ((unsigned)f2b(acc[13] * inv) << 16);
                o1.w = (unsigned)f2b(acc[14] * inv) | ((unsigned)f2b(acc[15] * inv) << 16);
                *(uint4*)op       = o0;
                *(uint4*)(op + 8) = o1;
            }

            if constexpr (NPHASE == 2) {
                const uint4 s = *(const uint4*)(&aggb[g][qi][h * 16]);
                asm volatile("" :: "v"(s.x), "v"(s.y), "v"(s.z), "v"(s.w));
            }
        }

        if constexpr (NPHASE >= 3) {
            __syncthreads();

            // ------------- Phase 3: out-projection ----------------------
            short8 aA[2][4];
            #pragma unroll
            for (int rt = 0; rt < 2; ++rt)
                #pragma unroll
                for (int ks = 0; ks < 4; ++ks)
                    aA[rt][ks] = *(const short8*)(&aggb[g][rt * 16 + r16][ks * 32 + kg * 8]);

            #pragma unroll
            for (int j = 0; j < 2; ++j) {
                const int ct = wv * 2 + j;            // 0..7
                const int c  = ct * 16 + r16;         // 0..127
                short8 bf[4];
                #pragma unroll
                for (int ks = 0; ks < 4; ++ks)
                    bf[ks] = load_frag_f32(Wout + (size_t)c * 128 + ks * 32 + kg * 8);
                const float bias_v = bout[c];
                #pragma unroll
                for (int rt = 0; rt < 2; ++rt) {
                    f32x4 oacc = {0.f, 0.f, 0.f, 0.f};
                    #pragma unroll
                    for (int ks = 0; ks < 4; ++ks)
                        oacc = __builtin_amdgcn_mfma_f32_16x16x32_bf16(aA[rt][ks], bf[ks], oacc, 0, 0, 0);
                    #pragma unroll
                    for (int r = 0; r < 4; ++r) {
                        const int row = base + rt * 16 + kg * 4 + r;
                        out[(size_t)row * 128 + c] = oacc[r] + bias_v;
                    }
                }
            }
        }

        // rep isolation: next rep rewrites LDS others may still be reading
        if (REPS > 1) __syncthreads();
    }
}

// =====================================================================
extern "C" void kernel_launch(void* const* d_in, const int* in_sizes, int n_in,
                              void* d_out, int out_size, void* d_ws, size_t ws_size,
                              hipStream_t stream)
{
    const float* x     = (const float*)d_in[0];   // [16384,128]
    const float* Win   = (const float*)d_in[1];   // [384,128]
    const float* bin   = (const float*)d_in[2];   // [384]
    const float* Wout  = (const float*)d_in[3];   // [128,128]
    const float* bout  = (const float*)d_in[4];   // [128]
    const float* alpha = (const float*)d_in[5];   // [16384,8]
    const float* dist2 = (const float*)d_in[6];   // [524288,16]

    float* out = (float*)d_out;

    // Diagnostic dispatches (do not touch d_out); per-dispatch rocprof rows
    // give phase-1 and phase-1+2 cost directly (divide dur by REPS).
    fused2_kernel<1, 6><<<dim3(256), 512, 0, stream>>>(
        x, Win, bin, Wout, bout, alpha, dist2, out);
    fused2_kernel<2, 3><<<dim3(256), 512, 0, stream>>>(
        x, Win, bin, Wout, bout, alpha, dist2, out);
    // The real (round-11) kernel: writes d_out, validated.
    fused2_kernel<3, 1><<<dim3(256), 512, 0, stream>>>(
        x, Win, bin, Wout, bout, alpha, dist2, out);
}

// Round 13
// 35.915 us; speedup vs baseline: 3.7837x; 3.7837x over previous
//
#include <hip/hip_runtime.h>
#include <hip/hip_bf16.h>

#define LOG2E_F 1.4426950408889634f

typedef __attribute__((ext_vector_type(8))) short short8;
typedef __attribute__((ext_vector_type(4))) float f32x4;
typedef __attribute__((ext_vector_type(2))) float f32x2;

__device__ inline unsigned short f2b(float f) {
    __hip_bfloat16 h = __float2bfloat16(f);   // RNE
    return *reinterpret_cast<unsigned short*>(&h);
}

__device__ inline short8 load_frag_f32(const float* p) {
    const float4 lo = *(const float4*)p;
    const float4 hi = *(const float4*)(p + 4);
    short8 r;
    r[0] = (short)f2b(lo.x); r[1] = (short)f2b(lo.y);
    r[2] = (short)f2b(lo.z); r[3] = (short)f2b(lo.w);
    r[4] = (short)f2b(hi.x); r[5] = (short)f2b(hi.y);
    r[6] = (short)f2b(hi.z); r[7] = (short)f2b(hi.w);
    return r;
}

__device__ inline f32x2 mk2(float a, float b) { f32x2 r; r.x = a; r.y = b; return r; }
#define PK_FMA(a, b, c) __builtin_elementwise_fma((a), (b), (c))
#define PK_MIN(a, b)    __builtin_elementwise_min((a), (b))

// =====================================================================
// Prologue: one-time f32 -> bf16 conversion of x, Win, Wout.
// Removes all per-block convert chains from the fused kernel's phase 1/3
// (measured: phase 1+2 VALU issue = 13.6us/SIMD; cvt chains are ~15% of it)
// =====================================================================
__global__ __launch_bounds__(256) void prep_kernel(
    const float* __restrict__ x, const float* __restrict__ Win,
    const float* __restrict__ Wout,
    unsigned short* __restrict__ xbf, unsigned short* __restrict__ winbf,
    unsigned short* __restrict__ woutbf)
{
    const int i = blockIdx.x * 256 + threadIdx.x;   // unit = 8 floats
    const float* src; unsigned short* dst; size_t off;
    if (i < 262144)       { src = x;    dst = xbf;    off = (size_t)i * 8; }
    else if (i < 268288)  { src = Win;  dst = winbf;  off = (size_t)(i - 262144) * 8; }
    else                  { src = Wout; dst = woutbf; off = (size_t)(i - 268288) * 8; }
    const short8 r = load_frag_f32(src + off);
    *(short8*)(dst + off) = r;
}

// =====================================================================
// Fused layer (R11 structure: 256 blocks = 1/CU, 512 thr = 2 systems).
// Changes vs R11: (a) A/B fragments loaded directly as bf16 (prologue),
// (b) phase-2 inner math in packed f32x2 (v_pk_fma/min) — dot, PV,
// min-reduce, exp-args, exp-sum all 2-wide. Semantics identical.
// =====================================================================
__global__ __launch_bounds__(512, 2) void fused2_kernel(
    const unsigned short* __restrict__ xbf, const unsigned short* __restrict__ winbf,
    const float* __restrict__ bin, const unsigned short* __restrict__ woutbf,
    const float* __restrict__ bout, const float* __restrict__ alpha,
    const float* __restrict__ dist2, float* __restrict__ out)
{
    __shared__ float qkvl[2][3][32][164];        // 123.0 KB
    __shared__ unsigned short aggb[2][32][136];  //  17.0 KB

    const int tid  = threadIdx.x;                // 0..511
    const int g    = tid >> 8;                   // system group 0/1
    const int t    = tid & 255;
    const int sys  = blockIdx.x * 2 + g;
    const int lane = t & 63;
    const int wv   = t >> 6;                     // wave within group, 0..3
    const int r16  = lane & 15;
    const int kg   = lane >> 4;
    const int base = sys << 5;

    // ---------------- Phase 1: QKV projection into LDS[g] --------------
    short8 af[2][4];
    #pragma unroll
    for (int rt = 0; rt < 2; ++rt)
        #pragma unroll
        for (int ks = 0; ks < 4; ++ks)
            af[rt][ks] = *(const short8*)(
                xbf + (size_t)(base + rt * 16 + r16) * 128 + ks * 32 + kg * 8);

    #pragma unroll
    for (int j = 0; j < 6; ++j) {
        const int ct = wv * 6 + j;            // 0..23 (wave-uniform)
        const int c  = ct * 16 + r16;         // global col 0..383
        short8 bf[4];
        #pragma unroll
        for (int ks = 0; ks < 4; ++ks)
            bf[ks] = *(const short8*)(winbf + (size_t)c * 128 + ks * 32 + kg * 8);
        const float bias_v = bin[c];
        const int   bufi   = ct >> 3;         // 0=q, 1=k, 2=v
        const int   hh     = ct & 7;
        const float scale  = (bufi == 0) ? (0.25f * LOG2E_F) : 1.0f;

        #pragma unroll
        for (int rt = 0; rt < 2; ++rt) {
            f32x4 acc = {0.f, 0.f, 0.f, 0.f};
            #pragma unroll
            for (int ks = 0; ks < 4; ++ks)
                acc = __builtin_amdgcn_mfma_f32_16x16x32_bf16(af[rt][ks], bf[ks], acc, 0, 0, 0);
            #pragma unroll
            for (int r = 0; r < 4; ++r) {
                const int atom = rt * 16 + kg * 4 + r;
                qkvl[g][bufi][atom][hh * 20 + r16] = (acc[r] + bias_v) * scale;
            }
        }
    }

    const int qi = t >> 3;
    const int h  = t & 7;
    const float al2 = alpha[(size_t)(base + qi) * 8 + h] * LOG2E_F;   // < 0
    const f32x2 al22 = mk2(al2, al2);

    __syncthreads();

    // ---------------- Phase 2: attention (packed f32x2 math) -----------
    f32x2 q2[8];
    {
        const float* qrow = &qkvl[g][0][qi][h * 20];
        #pragma unroll
        for (int d4 = 0; d4 < 4; ++d4) {
            const float4 tq = *(const float4*)(qrow + (d4 << 2));
            q2[d4 * 2 + 0] = mk2(tq.x, tq.y);
            q2[d4 * 2 + 1] = mk2(tq.z, tq.w);
        }
    }

    float den = 0.f;
    f32x2 acc2[8] = {};
    const float* dp = dist2 + (size_t)(sys * 1024 + qi * 32) * 16;

    #pragma unroll 4
    for (int kj = 0; kj < 32; ++kj, dp += 16) {
        // ---- lattice LSE, packed ----
        const float4 t0 = *(const float4*)(dp + 0);
        const float4 t1 = *(const float4*)(dp + 4);
        const float4 t2 = *(const float4*)(dp + 8);
        const float4 t3 = *(const float4*)(dp + 12);
        const f32x2 d2p[8] = {mk2(t0.x,t0.y), mk2(t0.z,t0.w), mk2(t1.x,t1.y), mk2(t1.z,t1.w),
                              mk2(t2.x,t2.y), mk2(t2.z,t2.w), mk2(t3.x,t3.y), mk2(t3.z,t3.w)};
        f32x2 mnA = PK_MIN(PK_MIN(d2p[0], d2p[1]), PK_MIN(d2p[2], d2p[3]));
        f32x2 mnB = PK_MIN(PK_MIN(d2p[4], d2p[5]), PK_MIN(d2p[6], d2p[7]));
        const f32x2 mn2 = PK_MIN(mnA, mnB);
        const float mn  = fminf(mn2.x, mn2.y);
        const float c0  = al2 * mn;                  // = max_r(al2*d2), al2 < 0
        const f32x2 nc02 = mk2(-c0, -c0);

        f32x2 ex[8];
        #pragma unroll
        for (int i = 0; i < 8; ++i) ex[i] = PK_FMA(al22, d2p[i], nc02);
        f32x2 es = mk2(__builtin_amdgcn_exp2f(ex[0].x), __builtin_amdgcn_exp2f(ex[0].y));
        #pragma unroll
        for (int i = 1; i < 8; ++i)
            es += mk2(__builtin_amdgcn_exp2f(ex[i].x), __builtin_amdgcn_exp2f(ex[i].y));
        const float ssum = es.x + es.y;              // in [1, 16]

        // ---- q.k dot from LDS, packed ----
        const float* kr = &qkvl[g][1][kj][h * 20];
        const float4 k0 = *(const float4*)(kr + 0);
        const float4 k1 = *(const float4*)(kr + 4);
        const float4 k2 = *(const float4*)(kr + 8);
        const float4 k3 = *(const float4*)(kr + 12);
        f32x2 dA = q2[0] * mk2(k0.x, k0.y);
        f32x2 dB = q2[1] * mk2(k0.z, k0.w);
        dA = PK_FMA(q2[2], mk2(k1.x, k1.y), dA);
        dB = PK_FMA(q2[3], mk2(k1.z, k1.w), dB);
        dA = PK_FMA(q2[4], mk2(k2.x, k2.y), dA);
        dB = PK_FMA(q2[5], mk2(k2.z, k2.w), dB);
        dA = PK_FMA(q2[6], mk2(k3.x, k3.y), dA);
        dB = PK_FMA(q2[7], mk2(k3.z, k3.w), dB);
        const float dot = (dA.x + dA.y) + (dB.x + dB.y);   // log2-domain

        // fixed-shift softmax (R8-R11 validated): b-16 in [~-83,-1]
        const float b = dot + c0;
        const float p = __builtin_amdgcn_exp2f(b - 16.0f) * ssum;
        den += p;
        const f32x2 p2 = mk2(p, p);

        // ---- PV accumulate, packed ----
        const float* vr = &qkvl[g][2][kj][h * 20];
        const float4 v0 = *(const float4*)(vr + 0);
        const float4 v1 = *(const float4*)(vr + 4);
        const float4 v2 = *(const float4*)(vr + 8);
        const float4 v3 = *(const float4*)(vr + 12);
        acc2[0] = PK_FMA(p2, mk2(v0.x, v0.y), acc2[0]);
        acc2[1] = PK_FMA(p2, mk2(v0.z, v0.w), acc2[1]);
        acc2[2] = PK_FMA(p2, mk2(v1.x, v1.y), acc2[2]);
        acc2[3] = PK_FMA(p2, mk2(v1.z, v1.w), acc2[3]);
        acc2[4] = PK_FMA(p2, mk2(v2.x, v2.y), acc2[4]);
        acc2[5] = PK_FMA(p2, mk2(v2.z, v2.w), acc2[5]);
        acc2[6] = PK_FMA(p2, mk2(v3.x, v3.y), acc2[6]);
        acc2[7] = PK_FMA(p2, mk2(v3.z, v3.w), acc2[7]);
    }

    // write normalized agg row (bf16) to LDS[g]
    {
        const float inv = 1.0f / den;
        const f32x2 inv2 = mk2(inv, inv);
        unsigned short* op = &aggb[g][qi][h * 16];
        uint4 o0, o1;
        f32x2 r0 = acc2[0] * inv2, r1 = acc2[1] * inv2;
        f32x2 r2 = acc2[2] * inv2, r3 = acc2[3] * inv2;
        f32x2 r4 = acc2[4] * inv2, r5 = acc2[5] * inv2;
        f32x2 r6 = acc2[6] * inv2, r7 = acc2[7] * inv2;
        o0.x = (unsigned)f2b(r0.x) | ((unsigned)f2b(r0.y) << 16);
        o0.y = (unsigned)f2b(r1.x) | ((unsigned)f2b(r1.y) << 16);
        o0.z = (unsigned)f2b(r2.x) | ((unsigned)f2b(r2.y) << 16);
        o0.w = (unsigned)f2b(r3.x) | ((unsigned)f2b(r3.y) << 16);
        o1.x = (unsigned)f2b(r4.x) | ((unsigned)f2b(r4.y) << 16);
        o1.y = (unsigned)f2b(r5.x) | ((unsigned)f2b(r5.y) << 16);
        o1.z = (unsigned)f2b(r6.x) | ((unsigned)f2b(r6.y) << 16);
        o1.w = (unsigned)f2b(r7.x) | ((unsigned)f2b(r7.y) << 16);
        *(uint4*)op       = o0;
        *(uint4*)(op + 8) = o1;
    }

    __syncthreads();

    // ---------------- Phase 3: out-projection --------------------------
    short8 aA[2][4];
    #pragma unroll
    for (int rt = 0; rt < 2; ++rt)
        #pragma unroll
        for (int ks = 0; ks < 4; ++ks)
            aA[rt][ks] = *(const short8*)(&aggb[g][rt * 16 + r16][ks * 32 + kg * 8]);

    #pragma unroll
    for (int j = 0; j < 2; ++j) {
        const int ct = wv * 2 + j;            // 0..7
        const int c  = ct * 16 + r16;         // 0..127
        short8 bf[4];
        #pragma unroll
        for (int ks = 0; ks < 4; ++ks)
            bf[ks] = *(const short8*)(woutbf + (size_t)c * 128 + ks * 32 + kg * 8);
        const float bias_v = bout[c];
        #pragma unroll
        for (int rt = 0; rt < 2; ++rt) {
            f32x4 oacc = {0.f, 0.f, 0.f, 0.f};
            #pragma unroll
            for (int ks = 0; ks < 4; ++ks)
                oacc = __builtin_amdgcn_mfma_f32_16x16x32_bf16(aA[rt][ks], bf[ks], oacc, 0, 0, 0);
            #pragma unroll
            for (int r = 0; r < 4; ++r) {
                const int row = base + rt * 16 + kg * 4 + r;
                out[(size_t)row * 128 + c] = oacc[r] + bias_v;
            }
        }
    }
}

// =====================================================================
extern "C" void kernel_launch(void* const* d_in, const int* in_sizes, int n_in,
                              void* d_out, int out_size, void* d_ws, size_t ws_size,
                              hipStream_t stream)
{
    const float* x     = (const float*)d_in[0];   // [16384,128]
    const float* Win   = (const float*)d_in[1];   // [384,128]
    const float* bin   = (const float*)d_in[2];   // [384]
    const float* Wout  = (const float*)d_in[3];   // [128,128]
    const float* bout  = (const float*)d_in[4];   // [128]
    const float* alpha = (const float*)d_in[5];   // [16384,8]
    const float* dist2 = (const float*)d_in[6];   // [524288,16]

    unsigned short* xbf    = (unsigned short*)d_ws;            // 4 MB
    unsigned short* winbf  = xbf + (size_t)16384 * 128;        // 96 KB
    unsigned short* woutbf = winbf + (size_t)384 * 128;        // 32 KB

    prep_kernel<<<dim3(1056), 256, 0, stream>>>(x, Win, Wout, xbf, winbf, woutbf);
    fused2_kernel<<<dim3(256), 512, 0, stream>>>(
        xbf, winbf, bin, woutbf, bout, alpha, dist2, (float*)d_out);
}